// Round 1
// baseline (887.424 us; speedup 1.0000x reference)
//
#include <hip/hip_runtime.h>
#include <cstddef>

#define HID 64
#define CLS 40

__device__ __forceinline__ float lrelu(float x) { return x >= 0.f ? x : 0.2f * x; }

// monotone float<->uint encoding for atomicMax on floats
__device__ __forceinline__ unsigned encf(float f) {
    unsigned u = __float_as_uint(f);
    return (u & 0x80000000u) ? ~u : (u | 0x80000000u);
}
__device__ __forceinline__ float decf(unsigned e) {
    unsigned u = (e & 0x80000000u) ? (e ^ 0x80000000u) : ~e;
    return __uint_as_float(u);
}
#define ENC_NEGINF 0x007FFFFFu  // encf(-inf)

// ---------------- degree init / count ----------------
__global__ __launch_bounds__(256) void k_deginit(float* degs, float* degd, int n) {
    int i = blockIdx.x * 256 + threadIdx.x;
    if (i < n) { degs[i] = 1.f; degd[i] = 1.f; }  // self-loop counts
}

__global__ __launch_bounds__(256) void k_count(const int* __restrict__ ei,
                                               float* degs, float* degd, int E) {
    int e = blockIdx.x * 256 + threadIdx.x;
    if (e < E) {
        atomicAdd(&degs[ei[e]], 1.f);
        atomicAdd(&degd[ei[E + e]], 1.f);
    }
}

// ---------------- GEMM: H[n,64] = X[n,K] @ W[64,K]^T ----------------
template <int K>
__global__ __launch_bounds__(256) void k_gemm(const float* __restrict__ X,
                                              const float* __restrict__ W,
                                              float* __restrict__ H, int n) {
    __shared__ float Wl[HID * K];
    int tid = threadIdx.x;
    for (int i = tid; i < HID * K; i += 256) Wl[i] = W[i];
    __syncthreads();
    int r = blockIdx.x * 256 + tid;
    if (r >= n) return;
    float acc[HID];
#pragma unroll
    for (int c = 0; c < HID; c++) acc[c] = 0.f;
    const float* xr = X + (size_t)r * K;
    for (int k = 0; k < K; k += 4) {
        float4 xv = *reinterpret_cast<const float4*>(xr + k);
#pragma unroll
        for (int c = 0; c < HID; c++) {
            float4 wv = *reinterpret_cast<const float4*>(&Wl[c * K + k]);
            acc[c] += xv.x * wv.x + xv.y * wv.y + xv.z * wv.z + xv.w * wv.w;
        }
    }
    float* hr = H + (size_t)r * HID;
#pragma unroll
    for (int c = 0; c < HID; c++) hr[c] = acc[c];
}

// ---------------- per-node scalars + softmax-state init ----------------
__global__ __launch_bounds__(256) void k_scalars(const float* __restrict__ H,
                                                 const float* __restrict__ aw,
                                                 const float* __restrict__ sw,
                                                 const float* __restrict__ degs,
                                                 const float* __restrict__ degd,
                                                 float* ds, float* dt, float* dssw, float* dtsw,
                                                 unsigned* mA, unsigned* mN,
                                                 float* sA, float* sN, int n) {
    __shared__ float w[256];  // [aw(128) | sw(128)]
    int tid = threadIdx.x;
    if (tid < 128) w[tid] = aw[tid];
    else w[tid] = sw[tid - 128];
    __syncthreads();
    int v = blockIdx.x * 256 + tid;
    if (v >= n) return;
    const float* h = H + (size_t)v * HID;
    float d0 = 0.f, d1 = 0.f, d2 = 0.f, d3 = 0.f;
#pragma unroll
    for (int k = 0; k < HID; k++) {
        float hv = h[k];
        d0 += hv * w[k];
        d1 += hv * w[64 + k];
        d2 += hv * w[128 + k];
        d3 += hv * w[192 + k];
    }
    ds[v] = d0;
    dt[v] = d1;
    dssw[v] = degs[v] * d2;
    dtsw[v] = degd[v] * d3;
    mA[v] = ENC_NEGINF;
    mN[v] = ENC_NEGINF;
    sA[v] = 0.f;
    sN[v] = 0.f;
}

// ---------------- acc init ----------------
__global__ __launch_bounds__(256) void k_accinit(unsigned* acc, int total) {
    int i = blockIdx.x * 256 + threadIdx.x;
    if (i < total) acc[i] = ENC_NEGINF;
}

// ---------------- edge pass 1: scores + segment max ----------------
__global__ __launch_bounds__(256) void k_e1(const int* __restrict__ ei,
                                            const float* __restrict__ norm,
                                            const float* __restrict__ ds,
                                            const float* __restrict__ dt,
                                            const float* __restrict__ dssw,
                                            const float* __restrict__ dtsw,
                                            const float* __restrict__ ab,
                                            const float* __restrict__ sb,
                                            float* __restrict__ simb,
                                            float* __restrict__ nsimb,
                                            unsigned* mA, unsigned* mN, int Et, int E) {
    int e = blockIdx.x * 256 + threadIdx.x;
    if (e >= Et) return;
    int s, d;
    if (e < E) { s = ei[e]; d = ei[E + e]; }
    else { s = d = e - E; }
    float nrm = norm[e];
    float sim = lrelu(nrm * (ds[s] + dt[d]) + ab[0]);
    float ns = lrelu(dssw[s] + dtsw[d] + sb[0]);
    simb[e] = sim;
    nsimb[e] = ns;
    atomicMax(&mA[s], encf(sim));
    atomicMax(&mN[s], encf(ns));
}

// ---------------- edge pass 2: segment sum of exp ----------------
__global__ __launch_bounds__(256) void k_e2(const int* __restrict__ ei,
                                            const float* __restrict__ simb,
                                            const float* __restrict__ nsimb,
                                            const unsigned* __restrict__ mA,
                                            const unsigned* __restrict__ mN,
                                            float* sA, float* sN, int Et, int E) {
    int e = blockIdx.x * 256 + threadIdx.x;
    if (e >= Et) return;
    int s = (e < E) ? ei[e] : e - E;
    atomicAdd(&sA[s], expf(simb[e] - decf(mA[s])));
    atomicAdd(&sN[s], expf(nsimb[e] - decf(mN[s])));
}

// ---------------- edge pass 3: weighted scatter-max (wave per edge) ----------------
__global__ __launch_bounds__(256) void k_e3(const int* __restrict__ ei,
                                            const float* __restrict__ H,
                                            const float* __restrict__ simb,
                                            const float* __restrict__ nsimb,
                                            const unsigned* __restrict__ mA,
                                            const unsigned* __restrict__ mN,
                                            const float* __restrict__ sA,
                                            const float* __restrict__ sN,
                                            const float* __restrict__ alpha,
                                            unsigned* acc, int Et, int E) {
    int widx = threadIdx.x >> 6;
    int lane = threadIdx.x & 63;
    int e = blockIdx.x * 4 + widx;
    if (e >= Et) return;
    int s, d;
    if (e < E) { s = ei[e]; d = ei[E + e]; }
    else { s = d = e - E; }
    float al = alpha[0];
    float a = expf(simb[e] - decf(mA[s])) / sA[s];
    float st = expf(nsimb[e] - decf(mN[s])) / sN[s];
    float w = al * a + (1.f - al) * st;
    float m = w * H[(size_t)s * HID + lane];
    atomicMax(&acc[(size_t)d * HID + lane], encf(m));
}

// ---------------- finalize layer: decode + bias + relu ----------------
__global__ __launch_bounds__(256) void k_final(const unsigned* __restrict__ acc,
                                               const float* __restrict__ bias,
                                               float* __restrict__ out, int total) {
    int i = blockIdx.x * 256 + threadIdx.x;
    if (i >= total) return;
    int k = i & (HID - 1);
    float val = decf(acc[i]) + bias[k];
    out[i] = fmaxf(val, 0.f);
}

// ---------------- logits + log_softmax ----------------
__global__ __launch_bounds__(256) void k_logits(const float* __restrict__ H,
                                                const float* __restrict__ OW,
                                                const float* __restrict__ OB,
                                                float* __restrict__ out, int n) {
    __shared__ float Wl[CLS * HID];
    __shared__ float Bl[CLS];
    int tid = threadIdx.x;
    for (int i = tid; i < CLS * HID; i += 256) Wl[i] = OW[i];
    if (tid < CLS) Bl[tid] = OB[tid];
    __syncthreads();
    int v = blockIdx.x * 256 + tid;
    if (v >= n) return;
    const float* h = H + (size_t)v * HID;
    float lg[CLS];
    for (int c = 0; c < CLS; c++) {
        float a = 0.f;
#pragma unroll
        for (int k = 0; k < HID; k++) a += h[k] * Wl[c * HID + k];
        lg[c] = a + Bl[c];
    }
    float m = -INFINITY;
#pragma unroll
    for (int c = 0; c < CLS; c++) m = fmaxf(m, lg[c]);
    float sum = 0.f;
#pragma unroll
    for (int c = 0; c < CLS; c++) sum += expf(lg[c] - m);
    float lse = m + logf(sum);
    float* o = out + (size_t)v * CLS;
#pragma unroll
    for (int c = 0; c < CLS; c++) o[c] = lg[c] - lse;
}

extern "C" void kernel_launch(void* const* d_in, const int* in_sizes, int n_in,
                              void* d_out, int out_size, void* d_ws, size_t ws_size,
                              hipStream_t stream) {
    const float* x   = (const float*)d_in[0];
    const int*   ei  = (const int*)d_in[1];
    const float* nrm = (const float*)d_in[2];
    const float* w0  = (const float*)d_in[3];
    const float* w1  = (const float*)d_in[4];
    const float* aw0 = (const float*)d_in[5];
    const float* ab0 = (const float*)d_in[6];
    const float* aw1 = (const float*)d_in[7];
    const float* ab1 = (const float*)d_in[8];
    const float* sw0 = (const float*)d_in[9];
    const float* sb0 = (const float*)d_in[10];
    const float* sw1 = (const float*)d_in[11];
    const float* sb1 = (const float*)d_in[12];
    const float* al0 = (const float*)d_in[13];
    const float* al1 = (const float*)d_in[14];
    const float* b0  = (const float*)d_in[15];
    const float* b1  = (const float*)d_in[16];
    const float* ow  = (const float*)d_in[17];
    const float* ob  = (const float*)d_in[18];
    float* out = (float*)d_out;

    int N = in_sizes[0] / 128;
    int E = in_sizes[1] / 2;
    int Et = E + N;

    float* ws = (float*)d_ws;
    size_t off = 0;
    float* degs = ws + off; off += N;
    float* degd = ws + off; off += N;
    float* ds   = ws + off; off += N;
    float* dt   = ws + off; off += N;
    float* dssw = ws + off; off += N;
    float* dtsw = ws + off; off += N;
    unsigned* mA = (unsigned*)(ws + off); off += N;
    unsigned* mN = (unsigned*)(ws + off); off += N;
    float* sA   = ws + off; off += N;
    float* sN   = ws + off; off += N;
    float* h    = ws + off; off += (size_t)N * HID;
    float* lay  = ws + off; off += (size_t)N * HID;
    unsigned* acc = (unsigned*)(ws + off); off += (size_t)N * HID;
    float* simb  = ws + off; off += Et;
    float* nsimb = ws + off; off += Et;

    int nbN = (N + 255) / 256;
    int nbE = (Et + 255) / 256;
    int nbE4 = (Et + 3) / 4;
    int nbH = (N * HID + 255) / 256;

    k_deginit<<<nbN, 256, 0, stream>>>(degs, degd, N);
    k_count<<<(E + 255) / 256, 256, 0, stream>>>(ei, degs, degd, E);

    for (int L = 0; L < 2; ++L) {
        const float* aw = L ? aw1 : aw0;
        const float* ab = L ? ab1 : ab0;
        const float* sw = L ? sw1 : sw0;
        const float* sb = L ? sb1 : sb0;
        const float* al = L ? al1 : al0;
        const float* bs = L ? b1 : b0;

        if (L == 0)
            k_gemm<128><<<nbN, 256, 0, stream>>>(x, w0, h, N);
        else
            k_gemm<64><<<nbN, 256, 0, stream>>>(lay, w1, h, N);

        k_scalars<<<nbN, 256, 0, stream>>>(h, aw, sw, degs, degd,
                                           ds, dt, dssw, dtsw, mA, mN, sA, sN, N);
        k_accinit<<<nbH, 256, 0, stream>>>(acc, N * HID);
        k_e1<<<nbE, 256, 0, stream>>>(ei, nrm, ds, dt, dssw, dtsw, ab, sb,
                                      simb, nsimb, mA, mN, Et, E);
        k_e2<<<nbE, 256, 0, stream>>>(ei, simb, nsimb, mA, mN, sA, sN, Et, E);
        k_e3<<<nbE4, 256, 0, stream>>>(ei, h, simb, nsimb, mA, mN, sA, sN, al,
                                       acc, Et, E);
        k_final<<<nbH, 256, 0, stream>>>(acc, bs, lay, N * HID);
    }

    k_logits<<<nbN, 256, 0, stream>>>(lay, ow, ob, out, N);
}

// Round 2
// 500.582 us; speedup vs baseline: 1.7728x; 1.7728x over previous
//
#include <hip/hip_runtime.h>
#include <cstddef>

#define HID 64
#define CLS 40

__device__ __forceinline__ float lrelu(float x) { return x >= 0.f ? x : 0.2f * x; }

__device__ __forceinline__ float wmax(float v) {
#pragma unroll
    for (int o = 32; o > 0; o >>= 1) v = fmaxf(v, __shfl_xor(v, o));
    return v;
}
__device__ __forceinline__ float wsum(float v) {
#pragma unroll
    for (int o = 32; o > 0; o >>= 1) v += __shfl_xor(v, o);
    return v;
}

// ---------------- degree init / count (int) ----------------
__global__ __launch_bounds__(256) void k_deginit(int* degS, int* degD, int n) {
    int i = blockIdx.x * 256 + threadIdx.x;
    if (i < n) { degS[i] = 1; degD[i] = 1; }  // self-loop
}

__global__ __launch_bounds__(256) void k_count(const int* __restrict__ ei,
                                               int* degS, int* degD, int E) {
    int e = blockIdx.x * 256 + threadIdx.x;
    if (e < E) {
        atomicAdd(&degS[ei[e]], 1);
        atomicAdd(&degD[ei[E + e]], 1);
    }
}

// ---------------- exclusive scan (3 kernels) ----------------
// scan1: per-block inclusive scan into off[], block totals into bsum[]
__global__ __launch_bounds__(1024) void k_scan1(const int* __restrict__ deg,
                                                int* __restrict__ off,
                                                int* __restrict__ bsum, int n) {
    __shared__ int buf[2][1024];
    int tid = threadIdx.x;
    int i = blockIdx.x * 1024 + tid;
    int v = (i < n) ? deg[i] : 0;
    int cur = 0;
    buf[0][tid] = v;
    __syncthreads();
#pragma unroll
    for (int o = 1; o < 1024; o <<= 1) {
        int t = buf[cur][tid];
        if (tid >= o) t += buf[cur][tid - o];
        buf[cur ^ 1][tid] = t;
        cur ^= 1;
        __syncthreads();
    }
    if (i < n) off[i] = buf[cur][tid];
    if (tid == 1023) bsum[blockIdx.x] = buf[cur][1023];
}

// scan2: serial exclusive scan of block sums (nb ~ 49)
__global__ void k_scan2(int* bsum, int nb) {
    if (threadIdx.x == 0 && blockIdx.x == 0) {
        int run = 0;
        for (int b = 0; b < nb; b++) { int t = bsum[b]; bsum[b] = run; run += t; }
    }
}

// scan3: off[i] = incl[i] - deg[i] + bsum[b]  (exclusive global); cur[i] = off[i]; off[n]=total
__global__ __launch_bounds__(1024) void k_scan3(const int* __restrict__ deg,
                                                int* __restrict__ off,
                                                int* __restrict__ cur,
                                                const int* __restrict__ bsum,
                                                int n, int total) {
    int i = blockIdx.x * 1024 + threadIdx.x;
    if (i < n) {
        int v = off[i] - deg[i] + bsum[blockIdx.x];
        off[i] = v;
        cur[i] = v;
    }
    if (i == 0) off[n] = total;
}

// ---------------- scatter into CSR (by src and by dst) ----------------
__global__ __launch_bounds__(256) void k_scatter(const int* __restrict__ ei,
                                                 int* curS, int* curD,
                                                 int* __restrict__ csrS_eid,
                                                 int* __restrict__ csrS_dst,
                                                 int* __restrict__ csrD_src,
                                                 int* __restrict__ csrD_wpos,
                                                 int Et, int E) {
    int e = blockIdx.x * 256 + threadIdx.x;
    if (e >= Et) return;
    int s, d;
    if (e < E) { s = ei[e]; d = ei[E + e]; }
    else { s = d = e - E; }
    int ps = atomicAdd(&curS[s], 1);
    int pd = atomicAdd(&curD[d], 1);
    csrS_eid[ps] = e;
    csrS_dst[ps] = d;
    csrD_src[pd] = s;
    csrD_wpos[pd] = ps;
}

// ---------------- GEMM: H = X @ W^T, fused per-node scalar dots ----------------
template <int K>
__global__ __launch_bounds__(256) void k_gemm(const float* __restrict__ X,
                                              const float* __restrict__ W,
                                              const float* __restrict__ aw,
                                              const float* __restrict__ sw,
                                              const int* __restrict__ degS,
                                              const int* __restrict__ degD,
                                              float* __restrict__ H,
                                              float* ds, float* dt, float* dssw, float* dtsw,
                                              int n) {
    __shared__ float Wl[HID * K];
    __shared__ float awl[128];
    __shared__ float swl[128];
    int tid = threadIdx.x;
    for (int i = tid; i < HID * K; i += 256) Wl[i] = W[i];
    if (tid < 128) awl[tid] = aw[tid];
    else swl[tid - 128] = sw[tid - 128];
    __syncthreads();
    int r = blockIdx.x * 256 + tid;
    if (r >= n) return;
    float acc[HID];
#pragma unroll
    for (int c = 0; c < HID; c++) acc[c] = 0.f;
    const float* xr = X + (size_t)r * K;
    for (int k = 0; k < K; k += 4) {
        float4 xv = *reinterpret_cast<const float4*>(xr + k);
#pragma unroll
        for (int c = 0; c < HID; c++) {
            float4 wv = *reinterpret_cast<const float4*>(&Wl[c * K + k]);
            acc[c] += xv.x * wv.x + xv.y * wv.y + xv.z * wv.z + xv.w * wv.w;
        }
    }
    float* hr = H + (size_t)r * HID;
    float d0 = 0.f, d1 = 0.f, d2 = 0.f, d3 = 0.f;
#pragma unroll
    for (int c = 0; c < HID; c++) {
        hr[c] = acc[c];
        d0 += acc[c] * awl[c];
        d1 += acc[c] * awl[64 + c];
        d2 += acc[c] * swl[c];
        d3 += acc[c] * swl[64 + c];
    }
    ds[r] = d0;
    dt[r] = d1;
    dssw[r] = (float)degS[r] * d2;
    dtsw[r] = (float)degD[r] * d3;
}

// ---------------- softmax by src: wave per node, atomic-free ----------------
__global__ __launch_bounds__(256) void k_soft(const int* __restrict__ offS,
                                              const int* __restrict__ csrS_eid,
                                              const int* __restrict__ csrS_dst,
                                              const float* __restrict__ norm,
                                              const float* __restrict__ ds,
                                              const float* __restrict__ dt,
                                              const float* __restrict__ dssw,
                                              const float* __restrict__ dtsw,
                                              const float* __restrict__ ab,
                                              const float* __restrict__ sb,
                                              const float* __restrict__ alpha,
                                              float* __restrict__ w, int n) {
    int node = blockIdx.x * 4 + (threadIdx.x >> 6);
    int lane = threadIdx.x & 63;
    if (node >= n) return;
    int beg = offS[node], end = offS[node + 1];
    int deg = end - beg;
    float ds_s = ds[node], dssw_s = dssw[node];
    float ab0 = ab[0], sb0 = sb[0], al = alpha[0];

    if (deg <= 64) {
        bool valid = lane < deg;
        float sim = -INFINITY, nsim = -INFINITY;
        int pos = beg + lane;
        if (valid) {
            int eid = csrS_eid[pos];
            int d = csrS_dst[pos];
            float nr = norm[eid];
            sim = lrelu(nr * (ds_s + dt[d]) + ab0);
            nsim = lrelu(dssw_s + dtsw[d] + sb0);
        }
        float mAv = wmax(sim), mNv = wmax(nsim);
        float eA = valid ? expf(sim - mAv) : 0.f;
        float eN = valid ? expf(nsim - mNv) : 0.f;
        float sAv = wsum(eA), sNv = wsum(eN);
        if (valid) w[pos] = al * eA / sAv + (1.f - al) * eN / sNv;
    } else {
        // generic (rare) path: 3 recompute passes
        float mAv = -INFINITY, mNv = -INFINITY;
        for (int base = 0; base < deg; base += 64) {
            int idx = base + lane;
            float sim = -INFINITY, nsim = -INFINITY;
            if (idx < deg) {
                int eid = csrS_eid[beg + idx];
                int d = csrS_dst[beg + idx];
                float nr = norm[eid];
                sim = lrelu(nr * (ds_s + dt[d]) + ab0);
                nsim = lrelu(dssw_s + dtsw[d] + sb0);
            }
            mAv = fmaxf(mAv, wmax(sim));
            mNv = fmaxf(mNv, wmax(nsim));
        }
        float sAv = 0.f, sNv = 0.f;
        for (int base = 0; base < deg; base += 64) {
            int idx = base + lane;
            float eA = 0.f, eN = 0.f;
            if (idx < deg) {
                int eid = csrS_eid[beg + idx];
                int d = csrS_dst[beg + idx];
                float nr = norm[eid];
                eA = expf(lrelu(nr * (ds_s + dt[d]) + ab0) - mAv);
                eN = expf(lrelu(dssw_s + dtsw[d] + sb0) - mNv);
            }
            sAv += wsum(eA);
            sNv += wsum(eN);
        }
        for (int base = 0; base < deg; base += 64) {
            int idx = base + lane;
            if (idx < deg) {
                int eid = csrS_eid[beg + idx];
                int d = csrS_dst[beg + idx];
                float nr = norm[eid];
                float eA = expf(lrelu(nr * (ds_s + dt[d]) + ab0) - mAv);
                float eN = expf(lrelu(dssw_s + dtsw[d] + sb0) - mNv);
                w[beg + idx] = al * eA / sAv + (1.f - al) * eN / sNv;
            }
        }
    }
}

// ---------------- aggregation by dst: wave per node, register max ----------------
__global__ __launch_bounds__(256) void k_aggr(const int* __restrict__ offD,
                                              const int* __restrict__ csrD_src,
                                              const int* __restrict__ csrD_wpos,
                                              const float* __restrict__ w,
                                              const float* __restrict__ H,
                                              const float* __restrict__ bias,
                                              float* __restrict__ out, int n) {
    int node = blockIdx.x * 4 + (threadIdx.x >> 6);
    int lane = threadIdx.x & 63;
    if (node >= n) return;
    int beg = offD[node];
    int deg = offD[node + 1] - beg;
    float m = -INFINITY;
    for (int base = 0; base < deg; base += 64) {
        int idx = base + lane;
        int s = 0;
        float wv = 0.f;
        if (idx < deg) {
            s = csrD_src[beg + idx];
            wv = w[csrD_wpos[beg + idx]];
        }
        int cnt = min(64, deg - base);
        for (int j = 0; j < cnt; j++) {
            int sj = __shfl(s, j);
            float wj = __shfl(wv, j);
            m = fmaxf(m, wj * H[(size_t)sj * HID + lane]);
        }
    }
    out[(size_t)node * HID + lane] = fmaxf(m + bias[lane], 0.f);
}

// ---------------- logits + log_softmax ----------------
__global__ __launch_bounds__(256) void k_logits(const float* __restrict__ H,
                                                const float* __restrict__ OW,
                                                const float* __restrict__ OB,
                                                float* __restrict__ out, int n) {
    __shared__ float Wl[CLS * HID];
    __shared__ float Bl[CLS];
    int tid = threadIdx.x;
    for (int i = tid; i < CLS * HID; i += 256) Wl[i] = OW[i];
    if (tid < CLS) Bl[tid] = OB[tid];
    __syncthreads();
    int v = blockIdx.x * 256 + tid;
    if (v >= n) return;
    const float* h = H + (size_t)v * HID;
    float lg[CLS];
    for (int c = 0; c < CLS; c++) {
        float a = 0.f;
#pragma unroll
        for (int k = 0; k < HID; k++) a += h[k] * Wl[c * HID + k];
        lg[c] = a + Bl[c];
    }
    float m = -INFINITY;
#pragma unroll
    for (int c = 0; c < CLS; c++) m = fmaxf(m, lg[c]);
    float sum = 0.f;
#pragma unroll
    for (int c = 0; c < CLS; c++) sum += expf(lg[c] - m);
    float lse = m + logf(sum);
    float* o = out + (size_t)v * CLS;
#pragma unroll
    for (int c = 0; c < CLS; c++) o[c] = lg[c] - lse;
}

extern "C" void kernel_launch(void* const* d_in, const int* in_sizes, int n_in,
                              void* d_out, int out_size, void* d_ws, size_t ws_size,
                              hipStream_t stream) {
    const float* x   = (const float*)d_in[0];
    const int*   ei  = (const int*)d_in[1];
    const float* nrm = (const float*)d_in[2];
    const float* w0  = (const float*)d_in[3];
    const float* w1  = (const float*)d_in[4];
    const float* aw0 = (const float*)d_in[5];
    const float* ab0 = (const float*)d_in[6];
    const float* aw1 = (const float*)d_in[7];
    const float* ab1 = (const float*)d_in[8];
    const float* sw0 = (const float*)d_in[9];
    const float* sb0 = (const float*)d_in[10];
    const float* sw1 = (const float*)d_in[11];
    const float* sb1 = (const float*)d_in[12];
    const float* al0 = (const float*)d_in[13];
    const float* al1 = (const float*)d_in[14];
    const float* b0  = (const float*)d_in[15];
    const float* b1  = (const float*)d_in[16];
    const float* ow  = (const float*)d_in[17];
    const float* ob  = (const float*)d_in[18];
    float* out = (float*)d_out;

    int N = in_sizes[0] / 128;
    int E = in_sizes[1] / 2;
    int Et = E + N;

    // workspace carve (4-byte words, 256B aligned blocks)
    char* base = (char*)d_ws;
    size_t off = 0;
    auto alloc = [&](size_t words) {
        void* p = base + off;
        off += (words * 4 + 255) & ~(size_t)255;
        return p;
    };
    int* degS = (int*)alloc(N);
    int* degD = (int*)alloc(N);
    int* offS = (int*)alloc(N + 1);
    int* offD = (int*)alloc(N + 1);
    int* curS = (int*)alloc(N);
    int* curD = (int*)alloc(N);
    int* bsum = (int*)alloc(128);
    int* csrS_eid  = (int*)alloc(Et);
    int* csrS_dst  = (int*)alloc(Et);
    int* csrD_src  = (int*)alloc(Et);
    int* csrD_wpos = (int*)alloc(Et);
    float* wgt  = (float*)alloc(Et);
    float* ds   = (float*)alloc(N);
    float* dt   = (float*)alloc(N);
    float* dssw = (float*)alloc(N);
    float* dtsw = (float*)alloc(N);
    float* h    = (float*)alloc((size_t)N * HID);
    float* lay  = (float*)alloc((size_t)N * HID);

    int nbN = (N + 255) / 256;
    int nbE = (Et + 255) / 256;
    int nbScan = (N + 1023) / 1024;
    int nbW = (N + 3) / 4;  // wave-per-node kernels, 4 waves/block

    // ---- CSR build (once) ----
    k_deginit<<<nbN, 256, 0, stream>>>(degS, degD, N);
    k_count<<<(E + 255) / 256, 256, 0, stream>>>(ei, degS, degD, E);
    k_scan1<<<nbScan, 1024, 0, stream>>>(degS, offS, bsum, N);
    k_scan2<<<1, 64, 0, stream>>>(bsum, nbScan);
    k_scan3<<<nbScan, 1024, 0, stream>>>(degS, offS, curS, bsum, N, Et);
    k_scan1<<<nbScan, 1024, 0, stream>>>(degD, offD, bsum, N);
    k_scan2<<<1, 64, 0, stream>>>(bsum, nbScan);
    k_scan3<<<nbScan, 1024, 0, stream>>>(degD, offD, curD, bsum, N, Et);
    k_scatter<<<nbE, 256, 0, stream>>>(ei, curS, curD, csrS_eid, csrS_dst,
                                       csrD_src, csrD_wpos, Et, E);

    for (int L = 0; L < 2; ++L) {
        const float* aw = L ? aw1 : aw0;
        const float* ab = L ? ab1 : ab0;
        const float* sw = L ? sw1 : sw0;
        const float* sb = L ? sb1 : sb0;
        const float* al = L ? al1 : al0;
        const float* bs = L ? b1 : b0;

        if (L == 0)
            k_gemm<128><<<nbN, 256, 0, stream>>>(x, w0, aw, sw, degS, degD,
                                                 h, ds, dt, dssw, dtsw, N);
        else
            k_gemm<64><<<nbN, 256, 0, stream>>>(lay, w1, aw, sw, degS, degD,
                                                h, ds, dt, dssw, dtsw, N);

        k_soft<<<nbW, 256, 0, stream>>>(offS, csrS_eid, csrS_dst, nrm,
                                        ds, dt, dssw, dtsw, ab, sb, al, wgt, N);
        k_aggr<<<nbW, 256, 0, stream>>>(offD, csrD_src, csrD_wpos, wgt, h,
                                        bs, lay, N);
    }

    k_logits<<<nbN, 256, 0, stream>>>(lay, ow, ob, out, N);
}

// Round 3
// 475.321 us; speedup vs baseline: 1.8670x; 1.0531x over previous
//
#include <hip/hip_runtime.h>
#include <cstddef>

#define HID 64
#define CLS 40

__device__ __forceinline__ float lrelu(float x) { return x >= 0.f ? x : 0.2f * x; }

__device__ __forceinline__ float wmax(float v) {
#pragma unroll
    for (int o = 32; o > 0; o >>= 1) v = fmaxf(v, __shfl_xor(v, o));
    return v;
}
__device__ __forceinline__ float wsum(float v) {
#pragma unroll
    for (int o = 32; o > 0; o >>= 1) v += __shfl_xor(v, o);
    return v;
}

// ---------------- degree init / count (int) ----------------
__global__ __launch_bounds__(256) void k_deginit(int* degS, int* degD, int n) {
    int i = blockIdx.x * 256 + threadIdx.x;
    if (i < n) { degS[i] = 1; degD[i] = 1; }  // self-loop
}

__global__ __launch_bounds__(256) void k_count(const int* __restrict__ ei,
                                               int* degS, int* degD, int E) {
    int e = blockIdx.x * 256 + threadIdx.x;
    if (e < E) {
        atomicAdd(&degS[ei[e]], 1);
        atomicAdd(&degD[ei[E + e]], 1);
    }
}

// ---------------- exclusive scan (3 kernels) ----------------
__global__ __launch_bounds__(1024) void k_scan1(const int* __restrict__ deg,
                                                int* __restrict__ off,
                                                int* __restrict__ bsum, int n) {
    __shared__ int buf[2][1024];
    int tid = threadIdx.x;
    int i = blockIdx.x * 1024 + tid;
    int v = (i < n) ? deg[i] : 0;
    int cur = 0;
    buf[0][tid] = v;
    __syncthreads();
#pragma unroll
    for (int o = 1; o < 1024; o <<= 1) {
        int t = buf[cur][tid];
        if (tid >= o) t += buf[cur][tid - o];
        buf[cur ^ 1][tid] = t;
        cur ^= 1;
        __syncthreads();
    }
    if (i < n) off[i] = buf[cur][tid];
    if (tid == 1023) bsum[blockIdx.x] = buf[cur][1023];
}

__global__ void k_scan2(int* bsum, int nb) {
    if (threadIdx.x == 0 && blockIdx.x == 0) {
        int run = 0;
        for (int b = 0; b < nb; b++) { int t = bsum[b]; bsum[b] = run; run += t; }
    }
}

__global__ __launch_bounds__(1024) void k_scan3(const int* __restrict__ deg,
                                                int* __restrict__ off,
                                                int* __restrict__ cur,
                                                const int* __restrict__ bsum,
                                                int n, int total) {
    int i = blockIdx.x * 1024 + threadIdx.x;
    if (i < n) {
        int v = off[i] - deg[i] + bsum[blockIdx.x];
        off[i] = v;
        cur[i] = v;
    }
    if (i == 0) off[n] = total;
}

// ---------------- scatter into CSR (packed int2 payloads) ----------------
// csrS[ps] = {dst, norm_bits}   (norm folded in; eid never needed downstream)
// csrD[pd] = {src, wpos}
__global__ __launch_bounds__(256) void k_scatter(const int* __restrict__ ei,
                                                 const float* __restrict__ norm,
                                                 int* curS, int* curD,
                                                 int2* __restrict__ csrS,
                                                 int2* __restrict__ csrD,
                                                 int Et, int E) {
    int e = blockIdx.x * 256 + threadIdx.x;
    if (e >= Et) return;
    int s, d;
    if (e < E) { s = ei[e]; d = ei[E + e]; }
    else { s = d = e - E; }
    float nr = norm[e];
    int ps = atomicAdd(&curS[s], 1);
    int pd = atomicAdd(&curD[d], 1);
    csrS[ps] = make_int2(d, __float_as_int(nr));
    csrD[pd] = make_int2(s, ps);
}

// ---------------- GEMM: H = X @ W^T, fused per-node scalar dots ----------------
template <int K>
__global__ __launch_bounds__(256) void k_gemm(const float* __restrict__ X,
                                              const float* __restrict__ W,
                                              const float* __restrict__ aw,
                                              const float* __restrict__ sw,
                                              const int* __restrict__ degS,
                                              const int* __restrict__ degD,
                                              float* __restrict__ H,
                                              float* ds, float* dt, float* dssw, float* dtsw,
                                              int n) {
    __shared__ float Wl[HID * K];
    __shared__ float awl[128];
    __shared__ float swl[128];
    int tid = threadIdx.x;
    for (int i = tid; i < HID * K; i += 256) Wl[i] = W[i];
    if (tid < 128) awl[tid] = aw[tid];
    else swl[tid - 128] = sw[tid - 128];
    __syncthreads();
    int r = blockIdx.x * 256 + tid;
    if (r >= n) return;
    float acc[HID];
#pragma unroll
    for (int c = 0; c < HID; c++) acc[c] = 0.f;
    const float* xr = X + (size_t)r * K;
    for (int k = 0; k < K; k += 4) {
        float4 xv = *reinterpret_cast<const float4*>(xr + k);
#pragma unroll
        for (int c = 0; c < HID; c++) {
            float4 wv = *reinterpret_cast<const float4*>(&Wl[c * K + k]);
            acc[c] += xv.x * wv.x + xv.y * wv.y + xv.z * wv.z + xv.w * wv.w;
        }
    }
    float* hr = H + (size_t)r * HID;
    float d0 = 0.f, d1 = 0.f, d2 = 0.f, d3 = 0.f;
#pragma unroll
    for (int c = 0; c < HID; c++) {
        hr[c] = acc[c];
        d0 += acc[c] * awl[c];
        d1 += acc[c] * awl[64 + c];
        d2 += acc[c] * swl[c];
        d3 += acc[c] * swl[64 + c];
    }
    ds[r] = d0;
    dt[r] = d1;
    dssw[r] = (float)degS[r] * d2;
    dtsw[r] = (float)degD[r] * d3;
}

// ---------------- softmax by src: wave per node, atomic-free ----------------
__global__ __launch_bounds__(256) void k_soft(const int* __restrict__ offS,
                                              const int2* __restrict__ csrS,
                                              const float* __restrict__ ds,
                                              const float* __restrict__ dt,
                                              const float* __restrict__ dssw,
                                              const float* __restrict__ dtsw,
                                              const float* __restrict__ ab,
                                              const float* __restrict__ sb,
                                              const float* __restrict__ alpha,
                                              float* __restrict__ w, int n) {
    int node = blockIdx.x * 4 + (threadIdx.x >> 6);
    int lane = threadIdx.x & 63;
    if (node >= n) return;
    int beg = offS[node], end = offS[node + 1];
    int deg = end - beg;
    float ds_s = ds[node], dssw_s = dssw[node];
    float ab0 = ab[0], sb0 = sb[0], al = alpha[0];

    if (deg <= 64) {
        bool valid = lane < deg;
        float sim = -INFINITY, nsim = -INFINITY;
        int pos = beg + lane;
        if (valid) {
            int2 c = csrS[pos];
            int d = c.x;
            float nr = __int_as_float(c.y);
            sim = lrelu(nr * (ds_s + dt[d]) + ab0);
            nsim = lrelu(dssw_s + dtsw[d] + sb0);
        }
        float mAv = wmax(sim), mNv = wmax(nsim);
        float eA = valid ? expf(sim - mAv) : 0.f;
        float eN = valid ? expf(nsim - mNv) : 0.f;
        float sAv = wsum(eA), sNv = wsum(eN);
        if (valid) w[pos] = al * eA / sAv + (1.f - al) * eN / sNv;
    } else {
        float mAv = -INFINITY, mNv = -INFINITY;
        for (int base = 0; base < deg; base += 64) {
            int idx = base + lane;
            float sim = -INFINITY, nsim = -INFINITY;
            if (idx < deg) {
                int2 c = csrS[beg + idx];
                float nr = __int_as_float(c.y);
                sim = lrelu(nr * (ds_s + dt[c.x]) + ab0);
                nsim = lrelu(dssw_s + dtsw[c.x] + sb0);
            }
            mAv = fmaxf(mAv, wmax(sim));
            mNv = fmaxf(mNv, wmax(nsim));
        }
        float sAv = 0.f, sNv = 0.f;
        for (int base = 0; base < deg; base += 64) {
            int idx = base + lane;
            float eA = 0.f, eN = 0.f;
            if (idx < deg) {
                int2 c = csrS[beg + idx];
                float nr = __int_as_float(c.y);
                eA = expf(lrelu(nr * (ds_s + dt[c.x]) + ab0) - mAv);
                eN = expf(lrelu(dssw_s + dtsw[c.x] + sb0) - mNv);
            }
            sAv += wsum(eA);
            sNv += wsum(eN);
        }
        for (int base = 0; base < deg; base += 64) {
            int idx = base + lane;
            if (idx < deg) {
                int2 c = csrS[beg + idx];
                float nr = __int_as_float(c.y);
                float eA = expf(lrelu(nr * (ds_s + dt[c.x]) + ab0) - mAv);
                float eN = expf(lrelu(dssw_s + dtsw[c.x] + sb0) - mNv);
                w[beg + idx] = al * eA / sAv + (1.f - al) * eN / sNv;
            }
        }
    }
}

// ---------------- aggregation by dst: wave per node, 4-way unrolled ----------------
__global__ __launch_bounds__(256) void k_aggr(const int* __restrict__ offD,
                                              const int2* __restrict__ csrD,
                                              const float* __restrict__ w,
                                              const float* __restrict__ H,
                                              const float* __restrict__ bias,
                                              float* __restrict__ out, int n) {
    int node = blockIdx.x * 4 + (threadIdx.x >> 6);
    int lane = threadIdx.x & 63;
    if (node >= n) return;
    int beg = offD[node];
    int deg = offD[node + 1] - beg;
    float m0 = -INFINITY, m1 = -INFINITY, m2 = -INFINITY, m3 = -INFINITY;
    for (int base = 0; base < deg; base += 64) {
        int idx = base + lane;
        int s = 0;
        float wv = 0.f;
        if (idx < deg) {
            int2 c = csrD[beg + idx];
            s = c.x;
            wv = w[c.y];
        }
        int cnt = min(64, deg - base);
        int cnt4 = cnt & ~3;
        for (int j = 0; j < cnt4; j += 4) {
            int s0 = __shfl(s, j), s1 = __shfl(s, j + 1),
                s2 = __shfl(s, j + 2), s3 = __shfl(s, j + 3);
            float w0 = __shfl(wv, j), w1 = __shfl(wv, j + 1),
                  w2 = __shfl(wv, j + 2), w3 = __shfl(wv, j + 3);
            float h0 = H[(size_t)s0 * HID + lane];
            float h1 = H[(size_t)s1 * HID + lane];
            float h2 = H[(size_t)s2 * HID + lane];
            float h3 = H[(size_t)s3 * HID + lane];
            m0 = fmaxf(m0, w0 * h0);
            m1 = fmaxf(m1, w1 * h1);
            m2 = fmaxf(m2, w2 * h2);
            m3 = fmaxf(m3, w3 * h3);
        }
        for (int j = cnt4; j < cnt; j++) {
            int sj = __shfl(s, j);
            float wj = __shfl(wv, j);
            m0 = fmaxf(m0, wj * H[(size_t)sj * HID + lane]);
        }
    }
    float m = fmaxf(fmaxf(m0, m1), fmaxf(m2, m3));
    out[(size_t)node * HID + lane] = fmaxf(m + bias[lane], 0.f);
}

// ---------------- logits + log_softmax ----------------
__global__ __launch_bounds__(256) void k_logits(const float* __restrict__ H,
                                                const float* __restrict__ OW,
                                                const float* __restrict__ OB,
                                                float* __restrict__ out, int n) {
    __shared__ float Wl[CLS * HID];
    __shared__ float Bl[CLS];
    int tid = threadIdx.x;
    for (int i = tid; i < CLS * HID; i += 256) Wl[i] = OW[i];
    if (tid < CLS) Bl[tid] = OB[tid];
    __syncthreads();
    int v = blockIdx.x * 256 + tid;
    if (v >= n) return;
    const float* h = H + (size_t)v * HID;
    float hreg[HID];
#pragma unroll
    for (int k = 0; k < HID; k += 4) {
        float4 hv = *reinterpret_cast<const float4*>(h + k);
        hreg[k] = hv.x; hreg[k + 1] = hv.y; hreg[k + 2] = hv.z; hreg[k + 3] = hv.w;
    }
    float lg[CLS];
    for (int c = 0; c < CLS; c++) {
        float a = 0.f;
#pragma unroll
        for (int k = 0; k < HID; k++) a += hreg[k] * Wl[c * HID + k];
        lg[c] = a + Bl[c];
    }
    float m = -INFINITY;
#pragma unroll
    for (int c = 0; c < CLS; c++) m = fmaxf(m, lg[c]);
    float sum = 0.f;
#pragma unroll
    for (int c = 0; c < CLS; c++) sum += expf(lg[c] - m);
    float lse = m + logf(sum);
    float* o = out + (size_t)v * CLS;
#pragma unroll
    for (int c = 0; c < CLS; c++) o[c] = lg[c] - lse;
}

extern "C" void kernel_launch(void* const* d_in, const int* in_sizes, int n_in,
                              void* d_out, int out_size, void* d_ws, size_t ws_size,
                              hipStream_t stream) {
    const float* x   = (const float*)d_in[0];
    const int*   ei  = (const int*)d_in[1];
    const float* nrm = (const float*)d_in[2];
    const float* w0  = (const float*)d_in[3];
    const float* w1  = (const float*)d_in[4];
    const float* aw0 = (const float*)d_in[5];
    const float* ab0 = (const float*)d_in[6];
    const float* aw1 = (const float*)d_in[7];
    const float* ab1 = (const float*)d_in[8];
    const float* sw0 = (const float*)d_in[9];
    const float* sb0 = (const float*)d_in[10];
    const float* sw1 = (const float*)d_in[11];
    const float* sb1 = (const float*)d_in[12];
    const float* al0 = (const float*)d_in[13];
    const float* al1 = (const float*)d_in[14];
    const float* b0  = (const float*)d_in[15];
    const float* b1  = (const float*)d_in[16];
    const float* ow  = (const float*)d_in[17];
    const float* ob  = (const float*)d_in[18];
    float* out = (float*)d_out;

    int N = in_sizes[0] / 128;
    int E = in_sizes[1] / 2;
    int Et = E + N;

    char* base = (char*)d_ws;
    size_t off = 0;
    auto alloc = [&](size_t bytes) {
        void* p = base + off;
        off += (bytes + 255) & ~(size_t)255;
        return p;
    };
    int* degS = (int*)alloc(N * 4);
    int* degD = (int*)alloc(N * 4);
    int* offS = (int*)alloc((N + 1) * 4);
    int* offD = (int*)alloc((N + 1) * 4);
    int* curS = (int*)alloc(N * 4);
    int* curD = (int*)alloc(N * 4);
    int* bsum = (int*)alloc(128 * 4);
    int2* csrS = (int2*)alloc((size_t)Et * 8);
    int2* csrD = (int2*)alloc((size_t)Et * 8);
    float* wgt  = (float*)alloc((size_t)Et * 4);
    float* ds   = (float*)alloc(N * 4);
    float* dt   = (float*)alloc(N * 4);
    float* dssw = (float*)alloc(N * 4);
    float* dtsw = (float*)alloc(N * 4);
    float* h    = (float*)alloc((size_t)N * HID * 4);
    float* lay  = (float*)alloc((size_t)N * HID * 4);

    int nbN = (N + 255) / 256;
    int nbE = (Et + 255) / 256;
    int nbScan = (N + 1023) / 1024;
    int nbW = (N + 3) / 4;

    // ---- CSR build (once) ----
    k_deginit<<<nbN, 256, 0, stream>>>(degS, degD, N);
    k_count<<<(E + 255) / 256, 256, 0, stream>>>(ei, degS, degD, E);
    k_scan1<<<nbScan, 1024, 0, stream>>>(degS, offS, bsum, N);
    k_scan2<<<1, 64, 0, stream>>>(bsum, nbScan);
    k_scan3<<<nbScan, 1024, 0, stream>>>(degS, offS, curS, bsum, N, Et);
    k_scan1<<<nbScan, 1024, 0, stream>>>(degD, offD, bsum, N);
    k_scan2<<<1, 64, 0, stream>>>(bsum, nbScan);
    k_scan3<<<nbScan, 1024, 0, stream>>>(degD, offD, curD, bsum, N, Et);
    k_scatter<<<nbE, 256, 0, stream>>>(ei, nrm, curS, curD, csrS, csrD, Et, E);

    for (int L = 0; L < 2; ++L) {
        const float* aw = L ? aw1 : aw0;
        const float* ab = L ? ab1 : ab0;
        const float* sw = L ? sw1 : sw0;
        const float* sb = L ? sb1 : sb0;
        const float* al = L ? al1 : al0;
        const float* bs = L ? b1 : b0;

        if (L == 0)
            k_gemm<128><<<nbN, 256, 0, stream>>>(x, w0, aw, sw, degS, degD,
                                                 h, ds, dt, dssw, dtsw, N);
        else
            k_gemm<64><<<nbN, 256, 0, stream>>>(lay, w1, aw, sw, degS, degD,
                                                h, ds, dt, dssw, dtsw, N);

        k_soft<<<nbW, 256, 0, stream>>>(offS, csrS, ds, dt, dssw, dtsw,
                                        ab, sb, al, wgt, N);
        k_aggr<<<nbW, 256, 0, stream>>>(offD, csrD, wgt, h, bs, lay, N);
    }

    k_logits<<<nbN, 256, 0, stream>>>(lay, ow, ob, out, N);
}

// Round 4
// 336.764 us; speedup vs baseline: 2.6352x; 1.4114x over previous
//
#include <hip/hip_runtime.h>
#include <hip/hip_fp16.h>
#include <cstddef>

#define HID 64
#define CLS 40

__device__ __forceinline__ float lrelu(float x) { return x >= 0.f ? x : 0.2f * x; }

__device__ __forceinline__ float wmax(float v) {
#pragma unroll
    for (int o = 32; o > 0; o >>= 1) v = fmaxf(v, __shfl_xor(v, o));
    return v;
}
__device__ __forceinline__ float wsum(float v) {
#pragma unroll
    for (int o = 32; o > 0; o >>= 1) v += __shfl_xor(v, o);
    return v;
}

// ---------------- degree init / count+rank ----------------
__global__ __launch_bounds__(256) void k_deginit(int* degS, int* degD, int n) {
    int i = blockIdx.x * 256 + threadIdx.x;
    if (i < n) { degS[i] = 1; degD[i] = 1; }  // self-loop occupies rank 0
}

// rank = atomicAdd old value (>=1 since init=1); self-loops implicitly rank 0
__global__ __launch_bounds__(256) void k_count(const int* __restrict__ ei,
                                               int* degS, int* degD,
                                               int* __restrict__ rankS,
                                               int* __restrict__ rankD, int E) {
    int e = blockIdx.x * 256 + threadIdx.x;
    if (e < E) {
        rankS[e] = atomicAdd(&degS[ei[e]], 1);
        rankD[e] = atomicAdd(&degD[ei[E + e]], 1);
    }
}

// ---------------- exclusive scan (3 kernels) ----------------
__global__ __launch_bounds__(1024) void k_scan1(const int* __restrict__ deg,
                                                int* __restrict__ off,
                                                int* __restrict__ bsum, int n) {
    __shared__ int buf[2][1024];
    int tid = threadIdx.x;
    int i = blockIdx.x * 1024 + tid;
    int v = (i < n) ? deg[i] : 0;
    int cur = 0;
    buf[0][tid] = v;
    __syncthreads();
#pragma unroll
    for (int o = 1; o < 1024; o <<= 1) {
        int t = buf[cur][tid];
        if (tid >= o) t += buf[cur][tid - o];
        buf[cur ^ 1][tid] = t;
        cur ^= 1;
        __syncthreads();
    }
    if (i < n) off[i] = buf[cur][tid];
    if (tid == 1023) bsum[blockIdx.x] = buf[cur][1023];
}

__global__ void k_scan2(int* bsum, int nb) {
    if (threadIdx.x == 0 && blockIdx.x == 0) {
        int run = 0;
        for (int b = 0; b < nb; b++) { int t = bsum[b]; bsum[b] = run; run += t; }
    }
}

__global__ __launch_bounds__(1024) void k_scan3(const int* __restrict__ deg,
                                                int* __restrict__ off,
                                                const int* __restrict__ bsum,
                                                int n, int total) {
    int i = blockIdx.x * 1024 + threadIdx.x;
    if (i < n) off[i] = off[i] - deg[i] + bsum[blockIdx.x];
    if (i == 0) off[n] = total;
}

// ---------------- scatter into CSR: XCD-partitioned, atomic-free ----------------
// group g = blockIdx%8 (maps to one XCD) commits only nodes in its 1/8 range,
// so each csr cache line is written by a single XCD's L2.
// csrS[ps] = {dst, norm_bits};  csrD[pd] = {src, ps}
__global__ __launch_bounds__(256) void k_scatter(const int* __restrict__ ei,
                                                 const float* __restrict__ norm,
                                                 const int* __restrict__ offS,
                                                 const int* __restrict__ offD,
                                                 const int* __restrict__ rankS,
                                                 const int* __restrict__ rankD,
                                                 int2* __restrict__ csrS,
                                                 int2* __restrict__ csrD,
                                                 int Et, int E, int N) {
    int grp = blockIdx.x & 7;
    int s_lo = (int)(((long long)grp * N) / 8);
    int s_hi = (int)(((long long)(grp + 1) * N) / 8);
    int start = (blockIdx.x >> 3) * 256 + threadIdx.x;
    int stride = (gridDim.x >> 3) * 256;
    for (int e = start; e < Et; e += stride) {
        int s, d, rs, rd;
        if (e < E) { s = ei[e]; d = ei[E + e]; rs = rankS[e]; rd = rankD[e]; }
        else { s = d = e - E; rs = 0; rd = 0; }
        bool doS = (s >= s_lo) & (s < s_hi);
        bool doD = (d >= s_lo) & (d < s_hi);
        if (doS | doD) {
            int ps = offS[s] + rs;
            if (doS) csrS[ps] = make_int2(d, __float_as_int(norm[e]));
            if (doD) csrD[offD[d] + rd] = make_int2(s, ps);
        }
    }
}

// ---------------- GEMM: Hh(fp16) = X @ W^T, fused per-node scalar dots ----------------
template <int K>
__global__ __launch_bounds__(256) void k_gemm(const float* __restrict__ X,
                                              const float* __restrict__ W,
                                              const float* __restrict__ aw,
                                              const float* __restrict__ sw,
                                              const int* __restrict__ degS,
                                              const int* __restrict__ degD,
                                              __half* __restrict__ Hh,
                                              float* ds, float* dt, float* dssw, float* dtsw,
                                              int n) {
    __shared__ float Wl[HID * K];
    __shared__ float awl[128];
    __shared__ float swl[128];
    int tid = threadIdx.x;
    for (int i = tid; i < HID * K; i += 256) Wl[i] = W[i];
    if (tid < 128) awl[tid] = aw[tid];
    else swl[tid - 128] = sw[tid - 128];
    __syncthreads();
    int r = blockIdx.x * 256 + tid;
    if (r >= n) return;
    float acc[HID];
#pragma unroll
    for (int c = 0; c < HID; c++) acc[c] = 0.f;
    const float* xr = X + (size_t)r * K;
    for (int k = 0; k < K; k += 4) {
        float4 xv = *reinterpret_cast<const float4*>(xr + k);
#pragma unroll
        for (int c = 0; c < HID; c++) {
            float4 wv = *reinterpret_cast<const float4*>(&Wl[c * K + k]);
            acc[c] += xv.x * wv.x + xv.y * wv.y + xv.z * wv.z + xv.w * wv.w;
        }
    }
    float d0 = 0.f, d1 = 0.f, d2 = 0.f, d3 = 0.f;
    __half hrow[HID];
#pragma unroll
    for (int c = 0; c < HID; c++) {
        hrow[c] = __float2half(acc[c]);
        d0 += acc[c] * awl[c];
        d1 += acc[c] * awl[64 + c];
        d2 += acc[c] * swl[c];
        d3 += acc[c] * swl[64 + c];
    }
    uint4* hd = reinterpret_cast<uint4*>(Hh + (size_t)r * HID);
    const uint4* hs = reinterpret_cast<const uint4*>(hrow);
#pragma unroll
    for (int i = 0; i < HID / 8; i++) hd[i] = hs[i];
    ds[r] = d0;
    dt[r] = d1;
    dssw[r] = (float)degS[r] * d2;
    dtsw[r] = (float)degD[r] * d3;
}

// ---------------- softmax by src: wave per node, atomic-free ----------------
__global__ __launch_bounds__(256) void k_soft(const int* __restrict__ offS,
                                              const int2* __restrict__ csrS,
                                              const float* __restrict__ ds,
                                              const float* __restrict__ dt,
                                              const float* __restrict__ dssw,
                                              const float* __restrict__ dtsw,
                                              const float* __restrict__ ab,
                                              const float* __restrict__ sb,
                                              const float* __restrict__ alpha,
                                              float* __restrict__ w, int n) {
    int node = blockIdx.x * 4 + (threadIdx.x >> 6);
    int lane = threadIdx.x & 63;
    if (node >= n) return;
    int beg = offS[node], end = offS[node + 1];
    int deg = end - beg;
    float ds_s = ds[node], dssw_s = dssw[node];
    float ab0 = ab[0], sb0 = sb[0], al = alpha[0];

    if (deg <= 64) {
        bool valid = lane < deg;
        float sim = -INFINITY, nsim = -INFINITY;
        int pos = beg + lane;
        if (valid) {
            int2 c = csrS[pos];
            float nr = __int_as_float(c.y);
            sim = lrelu(nr * (ds_s + dt[c.x]) + ab0);
            nsim = lrelu(dssw_s + dtsw[c.x] + sb0);
        }
        float mAv = wmax(sim), mNv = wmax(nsim);
        float eA = valid ? expf(sim - mAv) : 0.f;
        float eN = valid ? expf(nsim - mNv) : 0.f;
        float sAv = wsum(eA), sNv = wsum(eN);
        if (valid) w[pos] = al * eA / sAv + (1.f - al) * eN / sNv;
    } else {
        float mAv = -INFINITY, mNv = -INFINITY;
        for (int base = 0; base < deg; base += 64) {
            int idx = base + lane;
            float sim = -INFINITY, nsim = -INFINITY;
            if (idx < deg) {
                int2 c = csrS[beg + idx];
                float nr = __int_as_float(c.y);
                sim = lrelu(nr * (ds_s + dt[c.x]) + ab0);
                nsim = lrelu(dssw_s + dtsw[c.x] + sb0);
            }
            mAv = fmaxf(mAv, wmax(sim));
            mNv = fmaxf(mNv, wmax(nsim));
        }
        float sAv = 0.f, sNv = 0.f;
        for (int base = 0; base < deg; base += 64) {
            int idx = base + lane;
            float eA = 0.f, eN = 0.f;
            if (idx < deg) {
                int2 c = csrS[beg + idx];
                float nr = __int_as_float(c.y);
                eA = expf(lrelu(nr * (ds_s + dt[c.x]) + ab0) - mAv);
                eN = expf(lrelu(dssw_s + dtsw[c.x] + sb0) - mNv);
            }
            sAv += wsum(eA);
            sNv += wsum(eN);
        }
        for (int base = 0; base < deg; base += 64) {
            int idx = base + lane;
            if (idx < deg) {
                int2 c = csrS[beg + idx];
                float nr = __int_as_float(c.y);
                float eA = expf(lrelu(nr * (ds_s + dt[c.x]) + ab0) - mAv);
                float eN = expf(lrelu(dssw_s + dtsw[c.x] + sb0) - mNv);
                w[beg + idx] = al * eA / sAv + (1.f - al) * eN / sNv;
            }
        }
    }
}

// ---------------- aggregation by dst: wave per node, fp16 gather ----------------
__global__ __launch_bounds__(256) void k_aggr(const int* __restrict__ offD,
                                              const int2* __restrict__ csrD,
                                              const float* __restrict__ w,
                                              const __half* __restrict__ Hh,
                                              const float* __restrict__ bias,
                                              float* __restrict__ out, int n) {
    int node = blockIdx.x * 4 + (threadIdx.x >> 6);
    int lane = threadIdx.x & 63;
    if (node >= n) return;
    int beg = offD[node];
    int deg = offD[node + 1] - beg;
    float m0 = -INFINITY, m1 = -INFINITY, m2 = -INFINITY, m3 = -INFINITY;
    for (int base = 0; base < deg; base += 64) {
        int idx = base + lane;
        int s = 0;
        float wv = 0.f;
        if (idx < deg) {
            int2 c = csrD[beg + idx];
            s = c.x;
            wv = w[c.y];
        }
        int cnt = min(64, deg - base);
        int cnt4 = cnt & ~3;
        for (int j = 0; j < cnt4; j += 4) {
            int s0 = __shfl(s, j), s1 = __shfl(s, j + 1),
                s2 = __shfl(s, j + 2), s3 = __shfl(s, j + 3);
            float w0 = __shfl(wv, j), w1 = __shfl(wv, j + 1),
                  w2 = __shfl(wv, j + 2), w3 = __shfl(wv, j + 3);
            float h0 = __half2float(Hh[(size_t)s0 * HID + lane]);
            float h1 = __half2float(Hh[(size_t)s1 * HID + lane]);
            float h2 = __half2float(Hh[(size_t)s2 * HID + lane]);
            float h3 = __half2float(Hh[(size_t)s3 * HID + lane]);
            m0 = fmaxf(m0, w0 * h0);
            m1 = fmaxf(m1, w1 * h1);
            m2 = fmaxf(m2, w2 * h2);
            m3 = fmaxf(m3, w3 * h3);
        }
        for (int j = cnt4; j < cnt; j++) {
            int sj = __shfl(s, j);
            float wj = __shfl(wv, j);
            m0 = fmaxf(m0, wj * __half2float(Hh[(size_t)sj * HID + lane]));
        }
    }
    float m = fmaxf(fmaxf(m0, m1), fmaxf(m2, m3));
    out[(size_t)node * HID + lane] = fmaxf(m + bias[lane], 0.f);
}

// ---------------- logits + log_softmax ----------------
__global__ __launch_bounds__(256) void k_logits(const float* __restrict__ H,
                                                const float* __restrict__ OW,
                                                const float* __restrict__ OB,
                                                float* __restrict__ out, int n) {
    __shared__ float Wl[CLS * HID];
    __shared__ float Bl[CLS];
    int tid = threadIdx.x;
    for (int i = tid; i < CLS * HID; i += 256) Wl[i] = OW[i];
    if (tid < CLS) Bl[tid] = OB[tid];
    __syncthreads();
    int v = blockIdx.x * 256 + tid;
    if (v >= n) return;
    const float* h = H + (size_t)v * HID;
    float hreg[HID];
#pragma unroll
    for (int k = 0; k < HID; k += 4) {
        float4 hv = *reinterpret_cast<const float4*>(h + k);
        hreg[k] = hv.x; hreg[k + 1] = hv.y; hreg[k + 2] = hv.z; hreg[k + 3] = hv.w;
    }
    float lg[CLS];
    for (int c = 0; c < CLS; c++) {
        float a = 0.f;
#pragma unroll
        for (int k = 0; k < HID; k++) a += hreg[k] * Wl[c * HID + k];
        lg[c] = a + Bl[c];
    }
    float m = -INFINITY;
#pragma unroll
    for (int c = 0; c < CLS; c++) m = fmaxf(m, lg[c]);
    float sum = 0.f;
#pragma unroll
    for (int c = 0; c < CLS; c++) sum += expf(lg[c] - m);
    float lse = m + logf(sum);
    float* o = out + (size_t)v * CLS;
#pragma unroll
    for (int c = 0; c < CLS; c++) o[c] = lg[c] - lse;
}

extern "C" void kernel_launch(void* const* d_in, const int* in_sizes, int n_in,
                              void* d_out, int out_size, void* d_ws, size_t ws_size,
                              hipStream_t stream) {
    const float* x   = (const float*)d_in[0];
    const int*   ei  = (const int*)d_in[1];
    const float* nrm = (const float*)d_in[2];
    const float* w0  = (const float*)d_in[3];
    const float* w1  = (const float*)d_in[4];
    const float* aw0 = (const float*)d_in[5];
    const float* ab0 = (const float*)d_in[6];
    const float* aw1 = (const float*)d_in[7];
    const float* ab1 = (const float*)d_in[8];
    const float* sw0 = (const float*)d_in[9];
    const float* sb0 = (const float*)d_in[10];
    const float* sw1 = (const float*)d_in[11];
    const float* sb1 = (const float*)d_in[12];
    const float* al0 = (const float*)d_in[13];
    const float* al1 = (const float*)d_in[14];
    const float* b0  = (const float*)d_in[15];
    const float* b1  = (const float*)d_in[16];
    const float* ow  = (const float*)d_in[17];
    const float* ob  = (const float*)d_in[18];
    float* out = (float*)d_out;

    int N = in_sizes[0] / 128;
    int E = in_sizes[1] / 2;
    int Et = E + N;

    char* base = (char*)d_ws;
    size_t off = 0;
    auto alloc = [&](size_t bytes) {
        void* p = base + off;
        off += (bytes + 255) & ~(size_t)255;
        return p;
    };
    int* degS = (int*)alloc(N * 4);
    int* degD = (int*)alloc(N * 4);
    int* offS = (int*)alloc((N + 1) * 4);
    int* offD = (int*)alloc((N + 1) * 4);
    int* bsum = (int*)alloc(128 * 4);
    int* rankS = (int*)alloc((size_t)E * 4);
    int* rankD = (int*)alloc((size_t)E * 4);
    int2* csrS = (int2*)alloc((size_t)Et * 8);
    int2* csrD = (int2*)alloc((size_t)Et * 8);
    float* wgt  = (float*)alloc((size_t)Et * 4);
    float* ds   = (float*)alloc(N * 4);
    float* dt   = (float*)alloc(N * 4);
    float* dssw = (float*)alloc(N * 4);
    float* dtsw = (float*)alloc(N * 4);
    __half* Hh  = (__half*)alloc((size_t)N * HID * 2);
    float* lay  = (float*)alloc((size_t)N * HID * 4);

    int nbN = (N + 255) / 256;
    int nbScan = (N + 1023) / 1024;
    int nbW = (N + 3) / 4;

    // ---- CSR build (once) ----
    k_deginit<<<nbN, 256, 0, stream>>>(degS, degD, N);
    k_count<<<(E + 255) / 256, 256, 0, stream>>>(ei, degS, degD, rankS, rankD, E);
    k_scan1<<<nbScan, 1024, 0, stream>>>(degS, offS, bsum, N);
    k_scan2<<<1, 64, 0, stream>>>(bsum, nbScan);
    k_scan3<<<nbScan, 1024, 0, stream>>>(degS, offS, bsum, N, Et);
    k_scan1<<<nbScan, 1024, 0, stream>>>(degD, offD, bsum, N);
    k_scan2<<<1, 64, 0, stream>>>(bsum, nbScan);
    k_scan3<<<nbScan, 1024, 0, stream>>>(degD, offD, bsum, N, Et);
    k_scatter<<<2048, 256, 0, stream>>>(ei, nrm, offS, offD, rankS, rankD,
                                        csrS, csrD, Et, E, N);

    for (int L = 0; L < 2; ++L) {
        const float* aw = L ? aw1 : aw0;
        const float* ab = L ? ab1 : ab0;
        const float* sw = L ? sw1 : sw0;
        const float* sb = L ? sb1 : sb0;
        const float* al = L ? al1 : al0;
        const float* bs = L ? b1 : b0;

        if (L == 0)
            k_gemm<128><<<nbN, 256, 0, stream>>>(x, w0, aw, sw, degS, degD,
                                                 Hh, ds, dt, dssw, dtsw, N);
        else
            k_gemm<64><<<nbN, 256, 0, stream>>>(lay, w1, aw, sw, degS, degD,
                                                Hh, ds, dt, dssw, dtsw, N);

        k_soft<<<nbW, 256, 0, stream>>>(offS, csrS, ds, dt, dssw, dtsw,
                                        ab, sb, al, wgt, N);
        k_aggr<<<nbW, 256, 0, stream>>>(offD, csrD, wgt, Hh, bs, lay, N);
    }

    k_logits<<<nbN, 256, 0, stream>>>(lay, ow, ob, out, N);
}